// Round 7
// baseline (604.603 us; speedup 1.0000x reference)
//
#include <hip/hip_runtime.h>
#include <math.h>

// All tensors fp32. B=256, F=512, H=1024, C=1000.

// ---------------------------------------------------------------------------
// pool_all: ONE dispatch for all pooling.
//   blocks [0, NBB)        : big rows (s1..s4), wave per row, 8-deep unroll
//   blocks [NBB, NBB+NSB)  : rowlen-49 rows (s5 then ff), LDS staging
// Read wall ~2.7 TB/s combined L3+HBM (R2..R6 invariant).
// ---------------------------------------------------------------------------
struct PoolAll {
    const float* src[4];
    float*       dst[4];
    int n4[4];        // rowlen / 4
    int cum[4];       // inclusive prefix sum of rows (waves)
    float inv[4];
    const float* s5;
    const float* ff;
    float*       dst5;
    float*       dstf;
    int nbb;          // big blocks
    int rows5;        // s5 rows
};

__global__ __launch_bounds__(256) void pool_all_kernel(PoolAll S) {
    __shared__ float lds[64 * 49];
    if ((int)blockIdx.x < S.nbb) {
        // ---- big path: wave per row ----
        int gid  = blockIdx.x * 256 + threadIdx.x;
        int wave = gid >> 6;
        int lane = gid & 63;
        if (wave >= S.cum[3]) return;
        int s = 0;
        #pragma unroll
        for (int i = 0; i < 3; ++i) if (wave >= S.cum[i]) s = i + 1;
        int row = wave - (s == 0 ? 0 : S.cum[s - 1]);
        const int n4 = S.n4[s];
        const float4* p4 = (const float4*)(S.src[s]) + (size_t)row * n4;
        float a0 = 0.f, a1 = 0.f, a2 = 0.f, a3 = 0.f;
        float a4 = 0.f, a5 = 0.f, a6 = 0.f, a7 = 0.f;
        int k = lane;
        for (; k + 448 < n4; k += 512) {
            float4 v0 = p4[k];       float4 v1 = p4[k + 64];
            float4 v2 = p4[k + 128]; float4 v3 = p4[k + 192];
            float4 v4 = p4[k + 256]; float4 v5 = p4[k + 320];
            float4 v6 = p4[k + 384]; float4 v7 = p4[k + 448];
            a0 += (v0.x + v0.y) + (v0.z + v0.w);
            a1 += (v1.x + v1.y) + (v1.z + v1.w);
            a2 += (v2.x + v2.y) + (v2.z + v2.w);
            a3 += (v3.x + v3.y) + (v3.z + v3.w);
            a4 += (v4.x + v4.y) + (v4.z + v4.w);
            a5 += (v5.x + v5.y) + (v5.z + v5.w);
            a6 += (v6.x + v6.y) + (v6.z + v6.w);
            a7 += (v7.x + v7.y) + (v7.z + v7.w);
        }
        for (; k + 192 < n4; k += 256) {
            float4 v0 = p4[k];       float4 v1 = p4[k + 64];
            float4 v2 = p4[k + 128]; float4 v3 = p4[k + 192];
            a0 += (v0.x + v0.y) + (v0.z + v0.w);
            a1 += (v1.x + v1.y) + (v1.z + v1.w);
            a2 += (v2.x + v2.y) + (v2.z + v2.w);
            a3 += (v3.x + v3.y) + (v3.z + v3.w);
        }
        for (; k < n4; k += 64) {
            float4 v = p4[k];
            a0 += (v.x + v.y) + (v.z + v.w);
        }
        float acc = ((a0 + a1) + (a2 + a3)) + ((a4 + a5) + (a6 + a7));
        #pragma unroll
        for (int off = 32; off > 0; off >>= 1) acc += __shfl_down(acc, off, 64);
        if (lane == 0) S.dst[s][row] = acc * S.inv[s];
        return;
    }
    // ---- small path: 64 rows of 49 per block via LDS ----
    const int tid  = threadIdx.x;
    const int row0 = (blockIdx.x - S.nbb) * 64;
    const float* src;
    float* dst;
    int rbase;
    if (row0 < S.rows5) { src = S.s5; dst = S.dst5; rbase = row0; }
    else                { src = S.ff; dst = S.dstf; rbase = row0 - S.rows5; }
    const float4* p4 = (const float4*)(src + (size_t)rbase * 49);
    float4* l4 = (float4*)lds;
    float4 v0 = p4[tid];
    float4 v1 = p4[tid + 256];
    float4 v2 = p4[tid + 512];
    float4 v3;
    const bool t3 = (tid < 784 - 768);
    if (t3) v3 = p4[tid + 768];
    l4[tid]       = v0;
    l4[tid + 256] = v1;
    l4[tid + 512] = v2;
    if (t3) l4[tid + 768] = v3;
    __syncthreads();
    const int r  = tid >> 2;
    const int c0 = tid & 3;
    float s = 0.f;
    #pragma unroll
    for (int c = c0; c < 49; c += 4) s += lds[r * 49 + c];
    s += __shfl_down(s, 2, 64);
    s += __shfl_down(s, 1, 64);
    if (c0 == 0) dst[rbase + r] = s * (1.f / 49.f);
}

// ---------------------------------------------------------------------------
// fc_tile v3: LDS-tiled split-K SGEMM with FUSED input reduction.
//   XKS == 0 : X is a plain [M][K] activation.
//   XKS  > 0 : X is a partial slab [XKS][M][K]; the X-stage computes
//              relu(xbias[k] + sum_s X[s][m][k]) — i.e. the previous layer's
//              reduce_bias+ReLU is folded into this kernel's staging loads.
//   EPIB     : KS==1 path; epilogue adds `bias` (no relu) and writes Y [M][N].
// Tile 64m x 64n, TK=16, 4x4 micro/thread, float4 staging both operands,
// register prefetch of next K-step (loads issued before compute, summed at
// LDS-write time so XKS loads hide under the 256-FMA compute phase).
// ---------------------------------------------------------------------------
template <int XKS, bool EPIB>
__global__ __launch_bounds__(256) void fc_tile_kernel(const float* __restrict__ X,
        const float* __restrict__ xbias, const float* __restrict__ W,
        float* __restrict__ P, const float* __restrict__ bias,
        int M, int K, int N, int Kc, int ntiles) {
    __shared__ __align__(16) float Xs[16][68];   // [k][m]
    __shared__ __align__(16) float Ws[16][68];   // [k][n]
    const int tpk = 4 * ntiles;            // mtiles=4
    int bid = blockIdx.x;
    int ks  = bid / tpk;
    int rem = bid - ks * tpk;
    int mt  = rem / ntiles;
    int nt  = rem - mt * ntiles;
    const int m0 = mt * 64, n0 = nt * 64;
    const int k0 = ks * Kc;
    int k1 = k0 + Kc; if (k1 > K) k1 = K;

    const int tid = threadIdx.x;
    const int tm = tid & 15;               // micro-row group
    const int tn = tid >> 4;               // micro-col group
    const int xr = tid >> 2, xc = tid & 3; // X stage: row m0+xr, cols k+xc*4
    const int wr = tid >> 4, wc = tid & 15;// W stage: row k+wr, cols n0+wc*4
    const int nwc = n0 + wc * 4;
    const size_t MK = (size_t)M * K;
    const size_t xoff0 = (size_t)(m0 + xr) * K;

    float4 acc[4];
    #pragma unroll
    for (int r = 0; r < 4; ++r) acc[r] = make_float4(0.f, 0.f, 0.f, 0.f);

    const int NXV = (XKS > 0) ? XKS : 1;
    float4 xv[NXV];
    float4 wv;

    // prefetch first K-step
    {
        const size_t xo = xoff0 + k0 + xc * 4;
        #pragma unroll
        for (int ss = 0; ss < NXV; ++ss)
            xv[ss] = *(const float4*)(X + (size_t)ss * MK + xo);
        if (nwc + 3 < N) {
            wv = *(const float4*)(W + (size_t)(k0 + wr) * N + nwc);
        } else {
            wv.x = (nwc + 0 < N) ? W[(size_t)(k0 + wr) * N + nwc + 0] : 0.f;
            wv.y = (nwc + 1 < N) ? W[(size_t)(k0 + wr) * N + nwc + 1] : 0.f;
            wv.z = (nwc + 2 < N) ? W[(size_t)(k0 + wr) * N + nwc + 2] : 0.f;
            wv.w = (nwc + 3 < N) ? W[(size_t)(k0 + wr) * N + nwc + 3] : 0.f;
        }
    }

    for (int kt = k0; kt < k1; kt += 16) {
        __syncthreads();
        // finalize staged X value (sum partial slices + prev bias + relu)
        float4 xs = xv[0];
        if (XKS > 0) {
            #pragma unroll
            for (int ss = 1; ss < NXV; ++ss) {
                xs.x += xv[ss].x; xs.y += xv[ss].y;
                xs.z += xv[ss].z; xs.w += xv[ss].w;
            }
            float4 xb = *(const float4*)(xbias + kt + xc * 4);
            xs.x = fmaxf(xs.x + xb.x, 0.f);
            xs.y = fmaxf(xs.y + xb.y, 0.f);
            xs.z = fmaxf(xs.z + xb.z, 0.f);
            xs.w = fmaxf(xs.w + xb.w, 0.f);
        }
        Xs[xc * 4 + 0][xr] = xs.x;
        Xs[xc * 4 + 1][xr] = xs.y;
        Xs[xc * 4 + 2][xr] = xs.z;
        Xs[xc * 4 + 3][xr] = xs.w;
        *(float4*)&Ws[wr][wc * 4] = wv;
        __syncthreads();
        if (kt + 16 < k1) {                // issue next-step loads early
            const size_t xo = xoff0 + kt + 16 + xc * 4;
            #pragma unroll
            for (int ss = 0; ss < NXV; ++ss)
                xv[ss] = *(const float4*)(X + (size_t)ss * MK + xo);
            if (nwc + 3 < N) {
                wv = *(const float4*)(W + (size_t)(kt + 16 + wr) * N + nwc);
            } else {
                wv.x = (nwc + 0 < N) ? W[(size_t)(kt + 16 + wr) * N + nwc + 0] : 0.f;
                wv.y = (nwc + 1 < N) ? W[(size_t)(kt + 16 + wr) * N + nwc + 1] : 0.f;
                wv.z = (nwc + 2 < N) ? W[(size_t)(kt + 16 + wr) * N + nwc + 2] : 0.f;
                wv.w = (nwc + 3 < N) ? W[(size_t)(kt + 16 + wr) * N + nwc + 3] : 0.f;
            }
        }
        #pragma unroll
        for (int kk = 0; kk < 16; ++kk) {
            float4 xr4 = *(const float4*)&Xs[kk][tm * 4];
            float4 wr4 = *(const float4*)&Ws[kk][tn * 4];
            acc[0].x += xr4.x * wr4.x; acc[0].y += xr4.x * wr4.y;
            acc[0].z += xr4.x * wr4.z; acc[0].w += xr4.x * wr4.w;
            acc[1].x += xr4.y * wr4.x; acc[1].y += xr4.y * wr4.y;
            acc[1].z += xr4.y * wr4.z; acc[1].w += xr4.y * wr4.w;
            acc[2].x += xr4.z * wr4.x; acc[2].y += xr4.z * wr4.y;
            acc[2].z += xr4.z * wr4.z; acc[2].w += xr4.z * wr4.w;
            acc[3].x += xr4.w * wr4.x; acc[3].y += xr4.w * wr4.y;
            acc[3].z += xr4.w * wr4.z; acc[3].w += xr4.w * wr4.w;
        }
    }
    const int nbase = n0 + tn * 4;
    #pragma unroll
    for (int r = 0; r < 4; ++r) {
        int row = m0 + tm * 4 + r;
        float* pp = P + ((size_t)ks * M + row) * N + nbase;
        float4 v = acc[r];
        if (EPIB && nbase + 3 < N) {
            float4 bb = *(const float4*)(bias + nbase);
            v.x += bb.x; v.y += bb.y; v.z += bb.z; v.w += bb.w;
        }
        if (nbase + 3 < N) {
            *(float4*)pp = v;
        } else {
            float vv[4] = { v.x, v.y, v.z, v.w };
            for (int c = 0; c < 4; ++c)
                if (nbase + c < N) pp[c] = vv[c] + (EPIB ? bias[nbase + c] : 0.f);
        }
    }
}

// ---------------------------------------------------------------------------
// Batched projection GEMM: all 5 stages in one dispatch (TK=8, K=16..160).
// grid = (32 tiles, 5 stages). Bias fused.
// ---------------------------------------------------------------------------
struct ProjParams {
    const float* W[5];
    const float* bp[5];
    const float* g[5];
    const float* be[5];
    int K[5];
    int poff[5];
};

__global__ __launch_bounds__(256) void proj_gemm_kernel(ProjParams P,
        const float* __restrict__ pools, float* __restrict__ proj_out) {
    __shared__ __align__(16) float Xs[8][68];
    __shared__ __align__(16) float Ws[8][68];
    const int st = blockIdx.y;
    const int K  = P.K[st];
    const float* X = pools + P.poff[st];
    const float* W = P.W[st];
    const int N = 512;
    int bid = blockIdx.x;                  // 0..31: 4 mtiles x 8 ntiles
    int mt  = bid >> 3;
    int nt  = bid & 7;
    const int m0 = mt * 64, n0 = nt * 64;

    const int tid = threadIdx.x;
    const int tm = tid & 15;
    const int tn = tid >> 4;
    const int xa = tid >> 3, xb = tid & 7;
    const int wc = tid & 63, wb = tid >> 6;
    const int nw = n0 + wc;

    float4 acc[4];
    #pragma unroll
    for (int r = 0; r < 4; ++r) acc[r] = make_float4(0.f, 0.f, 0.f, 0.f);

    float x0, x1, w0v, w1v;
    x0  = X[(size_t)(m0 + xa) * K + xb];
    x1  = X[(size_t)(m0 + xa + 32) * K + xb];
    w0v = W[(size_t)wb * N + nw];
    w1v = W[(size_t)(wb + 4) * N + nw];

    for (int kt = 0; kt < K; kt += 8) {
        __syncthreads();
        Xs[xb][xa] = x0; Xs[xb][xa + 32] = x1;
        Ws[wb][wc] = w0v; Ws[wb + 4][wc] = w1v;
        __syncthreads();
        if (kt + 8 < K) {
            x0  = X[(size_t)(m0 + xa) * K + kt + 8 + xb];
            x1  = X[(size_t)(m0 + xa + 32) * K + kt + 8 + xb];
            w0v = W[(size_t)(kt + 8 + wb) * N + nw];
            w1v = W[(size_t)(kt + 8 + wb + 4) * N + nw];
        }
        #pragma unroll
        for (int kk = 0; kk < 8; ++kk) {
            float4 xr = *(const float4*)&Xs[kk][tm * 4];
            float4 wr = *(const float4*)&Ws[kk][tn * 4];
            acc[0].x += xr.x * wr.x; acc[0].y += xr.x * wr.y;
            acc[0].z += xr.x * wr.z; acc[0].w += xr.x * wr.w;
            acc[1].x += xr.y * wr.x; acc[1].y += xr.y * wr.y;
            acc[1].z += xr.y * wr.z; acc[1].w += xr.y * wr.w;
            acc[2].x += xr.z * wr.x; acc[2].y += xr.z * wr.y;
            acc[2].z += xr.z * wr.z; acc[2].w += xr.z * wr.w;
            acc[3].x += xr.w * wr.x; acc[3].y += xr.w * wr.y;
            acc[3].z += xr.w * wr.z; acc[3].w += xr.w * wr.w;
        }
    }
    const int nbase = n0 + tn * 4;
    float4 bb = *(const float4*)(P.bp[st] + nbase);
    float* op = proj_out + (size_t)st * 131072 + (size_t)(m0 + tm * 4) * N + nbase;
    #pragma unroll
    for (int r = 0; r < 4; ++r) {
        float4 v = acc[r];
        v.x += bb.x; v.y += bb.y; v.z += bb.z; v.w += bb.w;
        *(float4*)(op + (size_t)r * N) = v;
    }
}

// ---------------------------------------------------------------------------
// Gate fc3: reduces gate2's 16 partial slices inline (relu(bg2 + sum)),
// K=512 -> 5 logits, fused top-2 + softmax. 4 waves per batch.
// jax.lax.top_k tie rule: lower index wins on equality (strict >).
// ---------------------------------------------------------------------------
__global__ __launch_bounds__(256) void fc3_top2_kernel(const float* __restrict__ Xp,
        const float* __restrict__ xbias, const float* __restrict__ W,
        const float* __restrict__ bias, int* __restrict__ topi,
        float* __restrict__ wsm, float* __restrict__ out_gl,
        float* __restrict__ out_topi, float* __restrict__ out_w, int K) {
    const int b    = blockIdx.x;
    const int tid  = threadIdx.x;     // 0..255
    const int lane = tid & 63;
    const int wv   = tid >> 6;
    __shared__ float red[4][5];
    const size_t MK = (size_t)256 * K;
    float acc[5] = {0.f, 0.f, 0.f, 0.f, 0.f};
    for (int k = tid; k < K; k += 256) {
        float v = 0.f;
        #pragma unroll
        for (int s = 0; s < 16; ++s) v += Xp[(size_t)s * MK + (size_t)b * K + k];
        float xv = fmaxf(v + xbias[k], 0.f);
        const float* wr = W + (size_t)k * 5;
        acc[0] += xv * wr[0]; acc[1] += xv * wr[1]; acc[2] += xv * wr[2];
        acc[3] += xv * wr[3]; acc[4] += xv * wr[4];
    }
    #pragma unroll
    for (int off = 32; off > 0; off >>= 1) {
        #pragma unroll
        for (int j = 0; j < 5; ++j) acc[j] += __shfl_down(acc[j], off, 64);
    }
    if (lane == 0) {
        #pragma unroll
        for (int j = 0; j < 5; ++j) red[wv][j] = acc[j];
    }
    __syncthreads();
    if (tid == 0) {
        float v[5];
        #pragma unroll
        for (int j = 0; j < 5; ++j)
            v[j] = ((red[0][j] + red[1][j]) + (red[2][j] + red[3][j])) + bias[j];
        int i0 = 0;
        #pragma unroll
        for (int i = 1; i < 5; ++i) if (v[i] > v[i0]) i0 = i;
        int i1 = -1;
        #pragma unroll
        for (int i = 0; i < 5; ++i) {
            if (i == i0) continue;
            if (i1 < 0 || v[i] > v[i1]) i1 = i;
        }
        float e1 = __expf(v[i1] - v[i0]);          // v[i0] is the max
        float inv = 1.f / (1.f + e1);
        float w0 = inv, w1 = e1 * inv;
        topi[b * 2] = i0; topi[b * 2 + 1] = i1;
        wsm[b * 2] = w0;  wsm[b * 2 + 1] = w1;
        #pragma unroll
        for (int j = 0; j < 5; ++j) out_gl[b * 5 + j] = v[j];
        out_topi[b * 2]     = (float)i0;
        out_topi[b * 2 + 1] = (float)i1;
        out_w[b * 2]     = w0;
        out_w[b * 2 + 1] = w1;
    }
}

// ---------------------------------------------------------------------------
// mixln: gather the two selected projections per batch, LayerNorm + exact
// GELU + softmax-weighted sum. One block of 512 per batch element.
// ---------------------------------------------------------------------------
__global__ __launch_bounds__(512) void mixln_kernel(ProjParams P,
        const float* __restrict__ proj_out, const int* __restrict__ topi,
        const float* __restrict__ wsm, float* __restrict__ mix) {
    const int b = blockIdx.x;
    const int f = threadIdx.x;           // 0..511
    __shared__ float redS[8], redQ[8];
    __shared__ float s_mu, s_rstd;

    float acc = 0.f;
    for (int j = 0; j < 2; ++j) {
        __syncthreads();                 // protect red reuse across iterations
        const int st = topi[b * 2 + j];
        float h = proj_out[(size_t)st * 131072 + (size_t)b * 512 + f];

        // LayerNorm over 512 features (ddof=0)
        float s = h, q = h * h;
        #pragma unroll
        for (int off = 32; off > 0; off >>= 1) {
            s += __shfl_down(s, off, 64);
            q += __shfl_down(q, off, 64);
        }
        const int lane = threadIdx.x & 63, wid = threadIdx.x >> 6;
        if (lane == 0) { redS[wid] = s; redQ[wid] = q; }
        __syncthreads();
        if (threadIdx.x == 0) {
            float ts = 0.f, tq = 0.f;
            #pragma unroll
            for (int i = 0; i < 8; ++i) { ts += redS[i]; tq += redQ[i]; }
            float mu  = ts * (1.f / 512.f);
            float var = tq * (1.f / 512.f) - mu * mu;
            s_mu   = mu;
            s_rstd = rsqrtf(var + 1e-5f);
        }
        __syncthreads();

        float x  = (h - s_mu) * s_rstd * P.g[st][f] + P.be[st][f];
        float ge = 0.5f * x * (1.f + erff(x * 0.70710678118654752f));
        acc += wsm[b * 2 + j] * ge;
    }
    mix[(size_t)b * 512 + f] = acc;
}

// ---------------------------------------------------------------------------
extern "C" void kernel_launch(void* const* d_in, const int* in_sizes, int n_in,
                              void* d_out, int out_size, void* d_ws, size_t ws_size,
                              hipStream_t stream) {
    const int B = 256, F = 512, H = 1024, C = 1000;

    const float* s1 = (const float*)d_in[0];
    const float* s2 = (const float*)d_in[1];
    const float* s3 = (const float*)d_in[2];
    const float* s4 = (const float*)d_in[3];
    const float* s5 = (const float*)d_in[4];
    const float* ff = (const float*)d_in[5];
    const float *Wp[5], *bp[5], *g[5], *be[5];
    for (int i = 0; i < 5; ++i) {
        Wp[i] = (const float*)d_in[6 + 4 * i];
        bp[i] = (const float*)d_in[7 + 4 * i];
        g[i]  = (const float*)d_in[8 + 4 * i];
        be[i] = (const float*)d_in[9 + 4 * i];
    }
    const float* Wg1 = (const float*)d_in[26]; const float* bg1 = (const float*)d_in[27];
    const float* Wg2 = (const float*)d_in[28]; const float* bg2 = (const float*)d_in[29];
    const float* Wg3 = (const float*)d_in[30]; const float* bg3 = (const float*)d_in[31];
    const float* Wc1 = (const float*)d_in[32]; const float* bc1 = (const float*)d_in[33];
    const float* Wc2 = (const float*)d_in[34]; const float* bc2 = (const float*)d_in[35];
    const float* Wc3 = (const float*)d_in[36]; const float* bc3 = (const float*)d_in[37];

    // ---- workspace layout (fp32 elements) ----
    float* ws = (float*)d_ws;
    const int Ks[5]   = {16, 24, 40, 80, 160};
    const int poff[5] = {0, 4096, 10240, 20480, 40960};      // B*K prefix sums
    float* pools    = ws;                                     // 81920
    float* gate_in  = ws + 81920;                             // 245760
    float* wsm      = ws + 327680;                            // 512
    int*   topi     = (int*)(ws + 328192);                    // 512
    float* mix      = ws + 328704;                            // 131072
    float* proj_out = ws + 459776;                            // 655360 (5*B*F)
    float* slabA    = ws + 1115136;                           // 2097152 (16 x 256 x 512 max / 8 x 256 x 1024)
    float* slabB    = ws + 3212288;                           // 2097152
    // total <= 5309440 floats (~21 MB)

    float* out      = (float*)d_out;
    float* out_gl   = out + 256000;
    float* out_topi = out + 257280;
    float* out_w    = out + 257792;

    // ---- 1) ALL pooling in one dispatch ----
    {
        PoolAll S;
        const float* srcs[4] = { s1, s2, s3, s4 };
        const int rls[4]  = { 112 * 112, 56 * 56, 28 * 28, 14 * 14 };
        const int rows[4] = { B * 16, B * 24, B * 40, B * 80 };
        int cum = 0;
        for (int i = 0; i < 4; ++i) {
            S.src[i] = srcs[i]; S.dst[i] = pools + poff[i]; S.n4[i] = rls[i] / 4;
            cum += rows[i]; S.cum[i] = cum; S.inv[i] = 1.f / rls[i];
        }
        S.nbb   = (cum * 64) / 256;           // 10240 big blocks (cum=40960 waves)
        S.s5    = s5; S.ff = ff;
        S.dst5  = pools + poff[4]; S.dstf = gate_in;
        S.rows5 = B * 160;                    // 40960
        int small_blocks = (S.rows5 + B * 960) / 64;   // 4480
        pool_all_kernel<<<S.nbb + small_blocks, 256, 0, stream>>>(S);
    }

    // ---- 2) gate MLP (fused-reduce chain) ----
    // gate1: X=gate_in [256][960], KS=8 (Kc=128) -> slabA[8][256][1024]
    fc_tile_kernel<0, false><<<8 * 4 * 16, 256, 0, stream>>>(
        gate_in, nullptr, Wg1, slabA, nullptr, B, 960, H, 128, 16);
    // gate2: X=relu(bg1+sum8 slabA), KS=16 (Kc=64) -> slabB[16][256][512]
    fc_tile_kernel<8, false><<<16 * 4 * 8, 256, 0, stream>>>(
        slabA, bg1, Wg2, slabB, nullptr, B, H, H / 2, 64, 8);
    // fc3: reduce16(slabB)+relu inline, top-2 + softmax
    fc3_top2_kernel<<<B, 256, 0, stream>>>(slabB, bg2, Wg3, bg3, topi, wsm,
                                           out_gl, out_topi, out_w, H / 2);

    // ---- 3) all 5 projections (batched GEMM), then gather+LN+GELU+mix ----
    ProjParams P;
    for (int i = 0; i < 5; ++i) {
        P.W[i] = Wp[i]; P.bp[i] = bp[i]; P.g[i] = g[i]; P.be[i] = be[i];
        P.K[i] = Ks[i]; P.poff[i] = poff[i];
    }
    proj_gemm_kernel<<<dim3(32, 5), 256, 0, stream>>>(P, pools, proj_out);
    mixln_kernel<<<B, 512, 0, stream>>>(P, proj_out, topi, wsm, mix);

    // ---- 4) classifier MLP (fused-reduce chain) ----
    // cls1: X=mix [256][512], KS=8 (Kc=64) -> slabA[8][256][1024]
    fc_tile_kernel<0, false><<<8 * 4 * 16, 256, 0, stream>>>(
        mix, nullptr, Wc1, slabA, nullptr, B, F, H, 64, 16);
    // cls2: X=relu(bc1+sum8 slabA), KS=16 (Kc=64) -> slabB[16][256][512]
    fc_tile_kernel<8, false><<<16 * 4 * 8, 256, 0, stream>>>(
        slabA, bc1, Wc2, slabB, nullptr, B, H, H / 2, 64, 8);
    // cls3: X=relu(bc2+sum16 slabB), KS=1 (Kc=512), bias epilogue -> out
    fc_tile_kernel<16, true><<<1 * 4 * 16, 256, 0, stream>>>(
        slabB, bc2, Wc3, out, bc3, B, H / 2, C, 512, 16);
}